// Round 6
// baseline (526.854 us; speedup 1.0000x reference)
//
#include <hip/hip_runtime.h>
#include <math.h>

#define BSZ     2
#define LEN     4096
#define DMODEL  1024
#define DINNER  2048
#define DSTATE  128
#define NHEADS  32
#define HDIM    64
#define CONVDIM 2304
#define QC      64
#define NCHUNK  64
#define ROWS    (BSZ*LEN)          // 8192
#define SDIM    (HDIM*DSTATE)      // 8192
#define PB      136                // LDS pitch, natural [row][128+pad]
#define PT      72                 // LDS pitch, transposed [row][64+pad]
#define CGRP    (CONVDIM/8)        // 288 8-channel groups

typedef __attribute__((ext_vector_type(8))) short short8;
typedef __attribute__((ext_vector_type(4))) float f32x4;

__device__ __forceinline__ float silu_(float x){ return x / (1.0f + expf(-x)); }
__device__ __forceinline__ float sigm_(float x){ return 1.0f / (1.0f + expf(-x)); }
__device__ __forceinline__ float bf2f(unsigned short u){
    return __uint_as_float(((unsigned int)u) << 16);
}
__device__ __forceinline__ unsigned short f2bf(float f){
    unsigned int u = __float_as_uint(f);
    u = (u + 0x7fffu + ((u >> 16) & 1u)) >> 16;
    return (unsigned short)u;
}

__device__ __forceinline__ void gload16(const void* g, void* l) {
    __builtin_amdgcn_global_load_lds(
        (const __attribute__((address_space(1))) unsigned int*)g,
        (__attribute__((address_space(3))) unsigned int*)l, 16, 0, 0);
}

// f32 -> bf16 cast, 4 elems/thread
__global__ __launch_bounds__(256) void cast_bf16(const float* __restrict__ src,
                                                 unsigned short* __restrict__ dst,
                                                 int n4) {
    const int i = blockIdx.x * 256 + threadIdx.x;
    if (i >= n4) return;
    const float4 v = *(const float4*)(src + (size_t)i * 4);
    ushort4 o;
    o.x = f2bf(v.x); o.y = f2bf(v.y); o.z = f2bf(v.z); o.w = f2bf(v.w);
    *(ushort4*)(dst + (size_t)i * 4) = o;
}

// ---------------------------------------------------------------------------
// bf16 MFMA GEMM (m97 structure): C[M,N] = A[M,K] * B[N,K]^T, f32 accumulate.
// ---------------------------------------------------------------------------
template<bool BF16OUT>
__global__ __launch_bounds__(256) void gemm_bt_mfma(const unsigned short* __restrict__ A,
                                                    const unsigned short* __restrict__ B,
                                                    void* __restrict__ Cout,
                                                    int N, int K) {
    __shared__ unsigned short As[128 * 32];
    __shared__ unsigned short Bs[128 * 32];
    const int tid = threadIdx.x;
    const int wave = tid >> 6, lane = tid & 63;
    const int m0 = blockIdx.y * 128, n0 = blockIdx.x * 128;
    const int m_off = (wave >> 1) * 64, n_off = (wave & 1) * 64;

    f32x4 acc[4][4];
#pragma unroll
    for (int i = 0; i < 4; i++)
#pragma unroll
        for (int j = 0; j < 4; j++) acc[i][j] = (f32x4){0.f, 0.f, 0.f, 0.f};

    const int arow = m_off + (lane & 15);
    const int brow = n_off + (lane & 15);
    const int koff = (lane >> 4) * 16;

    for (int kt = 0; kt < K; kt += 32) {
#pragma unroll
        for (int u = 0; u < 2; u++) {
            const int f = u * 256 + tid;
            const int row = f >> 2;
            const int ke = (f & 3) * 8;
            gload16(A + (size_t)(m0 + row) * K + kt + ke, ((char*)As) + f * 16);
            gload16(B + (size_t)(n0 + row) * K + kt + ke, ((char*)Bs) + f * 16);
        }
        __syncthreads();
        short8 af[4], bfr[4];
#pragma unroll
        for (int i = 0; i < 4; i++)
            af[i] = *(const short8*)((const char*)As + (arow + i * 16) * 64 + koff);
#pragma unroll
        for (int j = 0; j < 4; j++)
            bfr[j] = *(const short8*)((const char*)Bs + (brow + j * 16) * 64 + koff);
#pragma unroll
        for (int i = 0; i < 4; i++)
#pragma unroll
            for (int j = 0; j < 4; j++)
                acc[i][j] = __builtin_amdgcn_mfma_f32_16x16x32_bf16(
                    af[i], bfr[j], acc[i][j], 0, 0, 0);
        __syncthreads();
    }

    const int crow = (lane >> 4) * 4;
    const int ccol = lane & 15;
#pragma unroll
    for (int i = 0; i < 4; i++)
#pragma unroll
        for (int j = 0; j < 4; j++) {
            const int n = n0 + n_off + j * 16 + ccol;
#pragma unroll
            for (int r = 0; r < 4; r++) {
                const int m = m0 + m_off + i * 16 + crow + r;
                if (BF16OUT)
                    ((unsigned short*)Cout)[(size_t)m * N + n] = f2bf(acc[i][j][r]);
                else
                    ((float*)Cout)[(size_t)m * N + n] = acc[i][j][r];
            }
        }
}

// ---------------------------------------------------------------------------
// Skinny dt projection, MFMA, fused sigmoid epilogue.
// ---------------------------------------------------------------------------
__global__ __launch_bounds__(256) void dtproj_mfma(const unsigned short* __restrict__ A,
                                                   const unsigned short* __restrict__ W,
                                                   const float* __restrict__ bias,
                                                   float* __restrict__ dtb,
                                                   int K) {
    __shared__ unsigned short As[128 * 32];
    __shared__ unsigned short Bs[32 * 32];
    const int tid = threadIdx.x;
    const int wave = tid >> 6, lane = tid & 63;
    const int quad = lane >> 4, l16 = lane & 15;
    const int m0 = blockIdx.x * 128;

    f32x4 acc[2][2];
#pragma unroll
    for (int i = 0; i < 2; i++)
#pragma unroll
        for (int j = 0; j < 2; j++) acc[i][j] = (f32x4){0.f, 0.f, 0.f, 0.f};

    for (int kt = 0; kt < K; kt += 32) {
#pragma unroll
        for (int u = 0; u < 2; u++) {
            const int f = u * 256 + tid;
            const int row = f >> 2, ke = (f & 3) * 8;
            gload16(A + (size_t)(m0 + row) * K + kt + ke, ((char*)As) + f * 16);
        }
        if (tid < 128) {
            const int row = tid >> 2, ke = (tid & 3) * 8;
            gload16(W + (size_t)row * K + kt + ke, ((char*)Bs) + tid * 16);
        }
        __syncthreads();
        short8 af[2], bfr[2];
#pragma unroll
        for (int i = 0; i < 2; i++)
            af[i] = *(const short8*)((const char*)As + (wave * 32 + i * 16 + l16) * 64 + quad * 16);
#pragma unroll
        for (int j = 0; j < 2; j++)
            bfr[j] = *(const short8*)((const char*)Bs + (j * 16 + l16) * 64 + quad * 16);
#pragma unroll
        for (int i = 0; i < 2; i++)
#pragma unroll
            for (int j = 0; j < 2; j++)
                acc[i][j] = __builtin_amdgcn_mfma_f32_16x16x32_bf16(
                    af[i], bfr[j], acc[i][j], 0, 0, 0);
        __syncthreads();
    }
#pragma unroll
    for (int i = 0; i < 2; i++)
#pragma unroll
        for (int j = 0; j < 2; j++) {
            const int h = j * 16 + l16;
            const float bh = bias[h];
#pragma unroll
            for (int r = 0; r < 4; r++) {
                const int m = m0 + wave * 32 + i * 16 + quad * 4 + r;
                dtb[(size_t)m * NHEADS + h] =
                    0.001f + 0.099f * sigm_(acc[i][j][r] + bh);
            }
        }
}

// ---------------------------------------------------------------------------
// Depthwise causal conv (K=4) + bias + SiLU, bf16 in/out, 8 channels/thread.
// One thread per (row, 8-channel group): 4x 16B loads, 1x 16B store.
// ---------------------------------------------------------------------------
__global__ __launch_bounds__(256) void conv_silu_v(const unsigned short* __restrict__ xbc,
                                                   const float* __restrict__ cw,
                                                   const float* __restrict__ cb,
                                                   unsigned short* __restrict__ xssm,
                                                   unsigned short* __restrict__ Bb,
                                                   unsigned short* __restrict__ Cb) {
    const long idx = (long)blockIdx.x * 256 + threadIdx.x;
    if (idx >= (long)ROWS * CGRP) return;
    const int g = (int)(idx % CGRP);
    const long row = idx / CGRP;
    const int l = (int)(row & (LEN - 1));      // position within sequence
    const int j0 = g * 8;

    float acc[8];
    float4 wv[8];
#pragma unroll
    for (int e = 0; e < 8; e++) {
        acc[e] = cb[j0 + e];
        wv[e] = *(const float4*)(cw + (size_t)(j0 + e) * 4);
    }
#pragma unroll
    for (int k = 0; k < 4; k++) {
        const int ls = l + k - 3;
        if (ls >= 0) {
            const short8 v = *(const short8*)(xbc + (row + (long)(k - 3)) * CONVDIM + j0);
            const float* w4 = (const float*)&wv[0];
#pragma unroll
            for (int e = 0; e < 8; e++)
                acc[e] += bf2f((unsigned short)v[e]) * ((const float*)&wv[e])[k];
            (void)w4;
        }
    }
    short8 o;
#pragma unroll
    for (int e = 0; e < 8; e++) o[e] = (short)f2bf(silu_(acc[e]));

    if (j0 < DINNER)
        *(short8*)(xssm + row * DINNER + j0) = o;
    else if (j0 < DINNER + DSTATE)
        *(short8*)(Bb + row * DSTATE + (j0 - DINNER)) = o;
    else
        *(short8*)(Cb + row * DSTATE + (j0 - DINNER - DSTATE)) = o;
}

__global__ __launch_bounds__(64) void acum_kernel(const float* __restrict__ dtb,
                                                  const float* __restrict__ A_log,
                                                  float* __restrict__ Acum) {
    const int c = blockIdx.x, h = blockIdx.y, b = blockIdx.z;
    const int q = threadIdx.x;
    const float Av = -expf(A_log[h]);
    float v = dtb[((size_t)b * LEN + c * QC + q) * NHEADS + h] * Av;
#pragma unroll
    for (int off = 1; off < 64; off <<= 1) {
        const float n = __shfl_up(v, off, 64);
        if (q >= off) v += n;
    }
    Acum[(((size_t)b * NHEADS + h) * NCHUNK + c) * QC + q] = v;
}

// ---------------------------------------------------------------------------
// MFMA chunk kernel (see R4 notes).
// ---------------------------------------------------------------------------
__global__ __launch_bounds__(256) void chunk_mfma(const unsigned short* __restrict__ xssm,
                                                  const unsigned short* __restrict__ Bb,
                                                  const unsigned short* __restrict__ Cb,
                                                  const float* __restrict__ dtb,
                                                  const float* __restrict__ Acum,
                                                  const float* __restrict__ Dskip,
                                                  unsigned short* __restrict__ Y,
                                                  unsigned short* __restrict__ states) {
    const int c = blockIdx.x, h = blockIdx.y, b = blockIdx.z;
    const int tid = threadIdx.x;
    const int wave = tid >> 6, lane = tid & 63;
    const int quad = lane >> 4, l16 = lane & 15;

    __shared__ __attribute__((aligned(16))) unsigned short Bsh[8704];
    __shared__ __attribute__((aligned(16))) unsigned short Csh[9216];
    __shared__ __attribute__((aligned(16))) unsigned short xTs[4608];
    __shared__ float ac[QC], dts[QC], decs[QC];

    const size_t rowbase = (size_t)b * LEN + c * QC;
    if (tid < QC) {
        ac[tid]  = Acum[(((size_t)b * NHEADS + h) * NCHUNK + c) * QC + tid];
        dts[tid] = dtb[(rowbase + tid) * NHEADS + h];
    }
#pragma unroll
    for (int u = 0; u < 4; u++) {
        const int vi = u * 256 + tid;
        const int s = vi >> 4, n0 = (vi & 15) * 8;
        *(short8*)&Bsh[s * PB + n0] = *(const short8*)(Bb + (rowbase + s) * DSTATE + n0);
        *(short8*)&Csh[s * PB + n0] = *(const short8*)(Cb + (rowbase + s) * DSTATE + n0);
    }
#pragma unroll
    for (int u = 0; u < 2; u++) {
        const int vi = u * 256 + tid;
        const int q = vi >> 3, p0 = (vi & 7) * 8;
        const short8 v = *(const short8*)(xssm + (rowbase + q) * DINNER + h * HDIM + p0);
#pragma unroll
        for (int j = 0; j < 8; j++) xTs[(p0 + j) * PT + q] = (unsigned short)v[j];
    }
    __syncthreads();
    if (tid < QC) decs[tid] = expf(ac[QC - 1] - ac[tid]) * dts[tid];

    // Phase 1: S = C . B^T
    f32x4 S[4];
#pragma unroll
    for (int j = 0; j < 4; j++) S[j] = (f32x4){0.f, 0.f, 0.f, 0.f};
    const int qa = wave * 16 + l16;
#pragma unroll
    for (int ks = 0; ks < 4; ks++) {
        const short8 a = *(const short8*)&Csh[qa * PB + ks * 32 + quad * 8];
#pragma unroll
        for (int j = 0; j < 4; j++) {
            const short8 bb = *(const short8*)&Bsh[(j * 16 + l16) * PB + ks * 32 + quad * 8];
            S[j] = __builtin_amdgcn_mfma_f32_16x16x32_bf16(a, bb, S[j], 0, 0, 0);
        }
    }
    unsigned short slv[4][4];
#pragma unroll
    for (int j = 0; j < 4; j++)
#pragma unroll
        for (int r = 0; r < 4; r++) {
            const int q = wave * 16 + quad * 4 + r, s = j * 16 + l16;
            const float v = (s <= q) ? S[j][r] * expf(ac[q] - ac[s]) * dts[s] : 0.f;
            slv[j][r] = f2bf(v);
        }
    __syncthreads();

    // B'[n][q] = B[q][n]*decs[q]
#pragma unroll
    for (int u = 0; u < 4; u++) {
        const int vi = u * 256 + tid;
        const int s = vi >> 4, n0 = (vi & 15) * 8;
        const short8 v = *(const short8*)&Bsh[s * PB + n0];
        const float d = decs[s];
#pragma unroll
        for (int j = 0; j < 8; j++)
            Csh[(n0 + j) * PT + s] = f2bf(bf2f((unsigned short)v[j]) * d);
    }
    __syncthreads();

#pragma unroll
    for (int j = 0; j < 4; j++)
#pragma unroll
        for (int r = 0; r < 4; r++)
            Bsh[(wave * 16 + quad * 4 + r) * PT + j * 16 + l16] = slv[j][r];
    __syncthreads();

    // Phase 2: Yd = SL . x
    f32x4 yd[4];
#pragma unroll
    for (int j = 0; j < 4; j++) yd[j] = (f32x4){0.f, 0.f, 0.f, 0.f};
#pragma unroll
    for (int ks = 0; ks < 2; ks++) {
        const short8 a = *(const short8*)&Bsh[qa * PT + ks * 32 + quad * 8];
#pragma unroll
        for (int j = 0; j < 4; j++) {
            const short8 xb = *(const short8*)&xTs[(j * 16 + l16) * PT + ks * 32 + quad * 8];
            yd[j] = __builtin_amdgcn_mfma_f32_16x16x32_bf16(a, xb, yd[j], 0, 0, 0);
        }
    }
    const float Dh = Dskip[h];
#pragma unroll
    for (int j = 0; j < 4; j++)
#pragma unroll
        for (int r = 0; r < 4; r++) {
            const int q = wave * 16 + quad * 4 + r, p = j * 16 + l16;
            const float v = yd[j][r] + Dh * bf2f(xTs[p * PT + q]);
            Y[(rowbase + q) * DINNER + h * HDIM + p] = f2bf(v);
        }

    // Phase 3: states = xT . B'
    f32x4 st[8];
#pragma unroll
    for (int j = 0; j < 8; j++) st[j] = (f32x4){0.f, 0.f, 0.f, 0.f};
#pragma unroll
    for (int ks = 0; ks < 2; ks++) {
        const short8 a = *(const short8*)&xTs[qa * PT + ks * 32 + quad * 8];
#pragma unroll
        for (int j = 0; j < 8; j++) {
            const short8 bb = *(const short8*)&Csh[(j * 16 + l16) * PT + ks * 32 + quad * 8];
            st[j] = __builtin_amdgcn_mfma_f32_16x16x32_bf16(a, bb, st[j], 0, 0, 0);
        }
    }
    const size_t sbase = (((size_t)b * NHEADS + h) * NCHUNK + c) * SDIM;
#pragma unroll
    for (int j = 0; j < 8; j++)
#pragma unroll
        for (int r = 0; r < 4; r++) {
            const int p = wave * 16 + quad * 4 + r, n = j * 16 + l16;
            states[sbase + (size_t)p * DSTATE + n] = f2bf(st[j][r]);
        }
}

// Sequential inter-chunk scan (bf16 storage, f32 carry)
__global__ __launch_bounds__(256) void scan_kernel(unsigned short* __restrict__ states,
                                                   const float* __restrict__ Acum) {
    __shared__ float dec[NCHUNK];
    const int bh = blockIdx.y;
    const int pn = blockIdx.x * 256 + threadIdx.x;
    if (threadIdx.x < NCHUNK)
        dec[threadIdx.x] = expf(Acum[((size_t)bh * NCHUNK + threadIdx.x) * QC + (QC - 1)]);
    __syncthreads();
    float carry = 0.f;
    const size_t base = (size_t)bh * NCHUNK * SDIM + pn;
    for (int c = 0; c < NCHUNK; c++) {
        const size_t idx = base + (size_t)c * SDIM;
        const float s = bf2f(states[idx]);
        states[idx] = f2bf(carry);
        carry = dec[c] * carry + s;
    }
}

// MFMA yo kernel: Yo[q][p] = eq[q] * sum_n C[q][n]*prev[p][n];  Y += Yo (bf16)
__global__ __launch_bounds__(256) void yo_mfma(const unsigned short* __restrict__ Cb,
                                               const unsigned short* __restrict__ prevs,
                                               const float* __restrict__ Acum,
                                               unsigned short* __restrict__ Y) {
    const int c = blockIdx.x, h = blockIdx.y, b = blockIdx.z;
    const int tid = threadIdx.x;
    const int wave = tid >> 6, lane = tid & 63;
    const int quad = lane >> 4, l16 = lane & 15;
    __shared__ __attribute__((aligned(16))) unsigned short Csh[8704];
    __shared__ __attribute__((aligned(16))) unsigned short Psh[8704];
    __shared__ float eq[QC];
    const size_t rowbase = (size_t)b * LEN + c * QC;
    const size_t pbase = (((size_t)b * NHEADS + h) * NCHUNK + c) * SDIM;
    if (tid < QC)
        eq[tid] = expf(Acum[(((size_t)b * NHEADS + h) * NCHUNK + c) * QC + tid]);
#pragma unroll
    for (int u = 0; u < 4; u++) {
        const int vi = u * 256 + tid;
        const int r = vi >> 4, n0 = (vi & 15) * 8;
        *(short8*)&Csh[r * PB + n0] = *(const short8*)(Cb + (rowbase + r) * DSTATE + n0);
        *(short8*)&Psh[r * PB + n0] = *(const short8*)(prevs + pbase + (size_t)r * DSTATE + n0);
    }
    __syncthreads();

    f32x4 acc[4];
#pragma unroll
    for (int j = 0; j < 4; j++) acc[j] = (f32x4){0.f, 0.f, 0.f, 0.f};
    const int qa = wave * 16 + l16;
#pragma unroll
    for (int ks = 0; ks < 4; ks++) {
        const short8 a = *(const short8*)&Csh[qa * PB + ks * 32 + quad * 8];
#pragma unroll
        for (int j = 0; j < 4; j++) {
            const short8 bb = *(const short8*)&Psh[(j * 16 + l16) * PB + ks * 32 + quad * 8];
            acc[j] = __builtin_amdgcn_mfma_f32_16x16x32_bf16(a, bb, acc[j], 0, 0, 0);
        }
    }
#pragma unroll
    for (int j = 0; j < 4; j++)
#pragma unroll
        for (int r = 0; r < 4; r++) {
            const int q = wave * 16 + quad * 4 + r, p = j * 16 + l16;
            const size_t off = (rowbase + q) * DINNER + h * HDIM + p;
            Y[off] = f2bf(bf2f(Y[off]) + eq[q] * acc[j][r]);
        }
}

// y = Y * silu(z); RMS-norm; write bf16 for GEMM2  (all bf16 I/O)
__global__ __launch_bounds__(256) void gate_rms(const unsigned short* __restrict__ Y,
                                                const unsigned short* __restrict__ zbf,
                                                const float* __restrict__ nw,
                                                unsigned short* __restrict__ ybf) {
    const int r = blockIdx.x, tid = threadIdx.x;
    float4 yv[2];
    float ss = 0.f;
#pragma unroll
    for (int u = 0; u < 2; u++) {
        const int col = u * 1024 + tid * 4;
        const ushort4 y4 = *(const ushort4*)(Y + (size_t)r * DINNER + col);
        const ushort4 z4 = *(const ushort4*)(zbf + (size_t)r * DINNER + col);
        float4 y;
        y.x = bf2f(y4.x) * silu_(bf2f(z4.x)); y.y = bf2f(y4.y) * silu_(bf2f(z4.y));
        y.z = bf2f(y4.z) * silu_(bf2f(z4.z)); y.w = bf2f(y4.w) * silu_(bf2f(z4.w));
        yv[u] = y;
        ss += y.x * y.x + y.y * y.y + y.z * y.z + y.w * y.w;
    }
#pragma unroll
    for (int off = 32; off; off >>= 1) ss += __shfl_xor(ss, off, 64);
    __shared__ float red[4];
    if ((tid & 63) == 0) red[tid >> 6] = ss;
    __syncthreads();
    ss = red[0] + red[1] + red[2] + red[3];
    const float scale = rsqrtf(ss / (float)DINNER + 1e-5f);
#pragma unroll
    for (int u = 0; u < 2; u++) {
        const int col = u * 1024 + tid * 4;
        const float4 w4 = *(const float4*)(nw + col);
        ushort4 o;
        o.x = f2bf(yv[u].x * scale * w4.x); o.y = f2bf(yv[u].y * scale * w4.y);
        o.z = f2bf(yv[u].z * scale * w4.z); o.w = f2bf(yv[u].w * scale * w4.w);
        *(ushort4*)(ybf + (size_t)r * DINNER + col) = o;
    }
}

// LayerNorm over D + residual (in place: outb == out is safe)
__global__ __launch_bounds__(256) void ln_res(const float* __restrict__ outb,
                                              const float* __restrict__ x,
                                              const float* __restrict__ lw,
                                              const float* __restrict__ lb,
                                              float* __restrict__ out) {
    const int r = blockIdx.x, tid = threadIdx.x;
    const int col = tid * 4;
    const float4 v = *(const float4*)(outb + (size_t)r * DMODEL + col);
    float s = v.x + v.y + v.z + v.w;
    float s2 = v.x * v.x + v.y * v.y + v.z * v.z + v.w * v.w;
#pragma unroll
    for (int off = 32; off; off >>= 1) {
        s += __shfl_xor(s, off, 64);
        s2 += __shfl_xor(s2, off, 64);
    }
    __shared__ float rs[4], rs2[4];
    if ((tid & 63) == 0) { rs[tid >> 6] = s; rs2[tid >> 6] = s2; }
    __syncthreads();
    s = rs[0] + rs[1] + rs[2] + rs[3];
    s2 = rs2[0] + rs2[1] + rs2[2] + rs2[3];
    const float mu = s / (float)DMODEL;
    const float var = s2 / (float)DMODEL - mu * mu;
    const float inv = rsqrtf(var + 1e-5f);
    const float4 xw = *(const float4*)(x + (size_t)r * DMODEL + col);
    const float4 w4 = *(const float4*)(lw + col);
    const float4 b4 = *(const float4*)(lb + col);
    float4 o;
    o.x = xw.x + (v.x - mu) * inv * w4.x + b4.x;
    o.y = xw.y + (v.y - mu) * inv * w4.y + b4.y;
    o.z = xw.z + (v.z - mu) * inv * w4.z + b4.z;
    o.w = xw.w + (v.w - mu) * inv * w4.w + b4.w;
    *(float4*)(out + (size_t)r * DMODEL + col) = o;
}

extern "C" void kernel_launch(void* const* d_in, const int* in_sizes, int n_in,
                              void* d_out, int out_size, void* d_ws, size_t ws_size,
                              hipStream_t stream) {
    const float* x          = (const float*)d_in[0];
    const float* in_proj_w  = (const float*)d_in[1];
    const float* conv_w     = (const float*)d_in[2];
    const float* conv_b     = (const float*)d_in[3];
    const float* dt_bias    = (const float*)d_in[4];
    const float* A_log      = (const float*)d_in[5];
    const float* D_skip     = (const float*)d_in[6];
    const float* norm_w     = (const float*)d_in[7];
    const float* out_proj_w = (const float*)d_in[8];
    const float* ln_w       = (const float*)d_in[9];
    const float* ln_b       = (const float*)d_in[10];
    float* out = (float*)d_out;
    float* ws = (float*)d_ws;

    // Workspace layout (float units). ~209 MB.
    size_t off = 0;
    unsigned short* zbf     = (unsigned short*)(ws + off); off += (size_t)ROWS * DINNER / 2;
    unsigned short* xssm_bf = (unsigned short*)(ws + off); off += (size_t)ROWS * DINNER / 2;
    unsigned short* uni     = (unsigned short*)(ws + off); off += (size_t)ROWS * CONVDIM / 2;
    unsigned short* Bb_bf   = (unsigned short*)(ws + off); off += (size_t)ROWS * DSTATE / 2;
    unsigned short* Cb_bf   = (unsigned short*)(ws + off); off += (size_t)ROWS * DSTATE / 2;
    float* dtb   = ws + off; off += (size_t)ROWS * NHEADS;
    float* Acum  = ws + off; off += (size_t)BSZ * NHEADS * NCHUNK * QC;
    unsigned short* x_bf  = (unsigned short*)(ws + off); off += (size_t)ROWS * DMODEL / 2;
    unsigned short* wi_bf = (unsigned short*)(ws + off); off += (size_t)4384 * DMODEL / 2;
    unsigned short* wo_bf = (unsigned short*)(ws + off); off += (size_t)DMODEL * DINNER / 2;
    unsigned short* states = (unsigned short*)(ws + off); off += (size_t)BSZ * NHEADS * NCHUNK * SDIM / 2;
    const size_t need_bytes = off * sizeof(float);
    if (ws_size < need_bytes) return;   // fail cleanly instead of faulting

    unsigned short* xbc_bf = uni;        // dies after conv
    unsigned short* Ybf    = uni;        // chunk output overlays dead xbc
    unsigned short* ybf    = xssm_bf;    // gate output overlays dead xssm

    // Casts
    cast_bf16<<<(ROWS * DMODEL / 4 + 255) / 256, 256, 0, stream>>>(x, x_bf, ROWS * DMODEL / 4);
    cast_bf16<<<(4384 * DMODEL / 4 + 255) / 256, 256, 0, stream>>>(in_proj_w, wi_bf, 4384 * DMODEL / 4);
    cast_bf16<<<(DMODEL * DINNER / 4 + 255) / 256, 256, 0, stream>>>(out_proj_w, wo_bf, DMODEL * DINNER / 4);

    // In-projection (bf16 MFMA): z (bf16), xBC (bf16), dt (MFMA + fused sigmoid)
    gemm_bt_mfma<true><<<dim3(DINNER / 128, ROWS / 128), 256, 0, stream>>>(
        x_bf, wi_bf, zbf, DINNER, DMODEL);
    gemm_bt_mfma<true><<<dim3(CONVDIM / 128, ROWS / 128), 256, 0, stream>>>(
        x_bf, wi_bf + (size_t)DINNER * DMODEL, xbc_bf, CONVDIM, DMODEL);
    dtproj_mfma<<<ROWS / 128, 256, 0, stream>>>(
        x_bf, wi_bf + (size_t)(DINNER + CONVDIM) * DMODEL, dt_bias, dtb, DMODEL);

    conv_silu_v<<<(int)(((long)ROWS * CGRP + 255) / 256), 256, 0, stream>>>(
        xbc_bf, conv_w, conv_b, xssm_bf, Bb_bf, Cb_bf);
    acum_kernel<<<dim3(NCHUNK, NHEADS, BSZ), 64, 0, stream>>>(dtb, A_log, Acum);
    chunk_mfma<<<dim3(NCHUNK, NHEADS, BSZ), 256, 0, stream>>>(
        xssm_bf, Bb_bf, Cb_bf, dtb, Acum, D_skip, Ybf, states);
    scan_kernel<<<dim3(SDIM / 256, BSZ * NHEADS), 256, 0, stream>>>(states, Acum);
    yo_mfma<<<dim3(NCHUNK, NHEADS, BSZ), 256, 0, stream>>>(Cb_bf, states, Acum, Ybf);
    gate_rms<<<ROWS, 256, 0, stream>>>(Ybf, zbf, norm_w, ybf);

    // Out-projection (bf16 MFMA) into d_out, then LN in place
    gemm_bt_mfma<false><<<dim3(DMODEL / 128, ROWS / 128), 256, 0, stream>>>(
        ybf, wo_bf, out, DMODEL, DINNER);
    ln_res<<<ROWS, 256, 0, stream>>>(out, x, ln_w, ln_b, out);
}

// Round 7
// 475.388 us; speedup vs baseline: 1.1083x; 1.1083x over previous
//
#include <hip/hip_runtime.h>
#include <math.h>

#define BSZ     2
#define LEN     4096
#define DMODEL  1024
#define DINNER  2048
#define DSTATE  128
#define NHEADS  32
#define HDIM    64
#define CONVDIM 2304
#define QC      64
#define NCHUNK  64
#define ROWS    (BSZ*LEN)          // 8192
#define SDIM    (HDIM*DSTATE)      // 8192
#define PB      136                // LDS pitch, natural [row][128+pad]
#define PT      72                 // LDS pitch, transposed [row][64+pad]
#define CGRP    (CONVDIM/8)        // 288 8-channel groups

typedef __attribute__((ext_vector_type(8))) short short8;
typedef __attribute__((ext_vector_type(4))) float f32x4;

__device__ __forceinline__ float silu_(float x){ return x / (1.0f + expf(-x)); }
__device__ __forceinline__ float sigm_(float x){ return 1.0f / (1.0f + expf(-x)); }
__device__ __forceinline__ float bf2f(unsigned short u){
    return __uint_as_float(((unsigned int)u) << 16);
}
__device__ __forceinline__ unsigned short f2bf(float f){
    unsigned int u = __float_as_uint(f);
    u = (u + 0x7fffu + ((u >> 16) & 1u)) >> 16;
    return (unsigned short)u;
}

__device__ __forceinline__ void gload16(const void* g, void* l) {
    __builtin_amdgcn_global_load_lds(
        (const __attribute__((address_space(1))) unsigned int*)g,
        (__attribute__((address_space(3))) unsigned int*)l, 16, 0, 0);
}

// f32 -> bf16 cast, 4 elems/thread
__global__ __launch_bounds__(256) void cast_bf16(const float* __restrict__ src,
                                                 unsigned short* __restrict__ dst,
                                                 int n4) {
    const int i = blockIdx.x * 256 + threadIdx.x;
    if (i >= n4) return;
    const float4 v = *(const float4*)(src + (size_t)i * 4);
    ushort4 o;
    o.x = f2bf(v.x); o.y = f2bf(v.y); o.z = f2bf(v.z); o.w = f2bf(v.w);
    *(ushort4*)(dst + (size_t)i * 4) = o;
}

// ---------------------------------------------------------------------------
// bf16 MFMA GEMM (m97 structure): C[M,N] = A[M,K] * B[N,K]^T, f32 accumulate.
// ---------------------------------------------------------------------------
template<bool BF16OUT>
__global__ __launch_bounds__(256) void gemm_bt_mfma(const unsigned short* __restrict__ A,
                                                    const unsigned short* __restrict__ B,
                                                    void* __restrict__ Cout,
                                                    int N, int K) {
    __shared__ unsigned short As[128 * 32];
    __shared__ unsigned short Bs[128 * 32];
    const int tid = threadIdx.x;
    const int wave = tid >> 6, lane = tid & 63;
    const int m0 = blockIdx.y * 128, n0 = blockIdx.x * 128;
    const int m_off = (wave >> 1) * 64, n_off = (wave & 1) * 64;

    f32x4 acc[4][4];
#pragma unroll
    for (int i = 0; i < 4; i++)
#pragma unroll
        for (int j = 0; j < 4; j++) acc[i][j] = (f32x4){0.f, 0.f, 0.f, 0.f};

    const int arow = m_off + (lane & 15);
    const int brow = n_off + (lane & 15);
    const int koff = (lane >> 4) * 16;

    for (int kt = 0; kt < K; kt += 32) {
#pragma unroll
        for (int u = 0; u < 2; u++) {
            const int f = u * 256 + tid;
            const int row = f >> 2;
            const int ke = (f & 3) * 8;
            gload16(A + (size_t)(m0 + row) * K + kt + ke, ((char*)As) + f * 16);
            gload16(B + (size_t)(n0 + row) * K + kt + ke, ((char*)Bs) + f * 16);
        }
        __syncthreads();
        short8 af[4], bfr[4];
#pragma unroll
        for (int i = 0; i < 4; i++)
            af[i] = *(const short8*)((const char*)As + (arow + i * 16) * 64 + koff);
#pragma unroll
        for (int j = 0; j < 4; j++)
            bfr[j] = *(const short8*)((const char*)Bs + (brow + j * 16) * 64 + koff);
#pragma unroll
        for (int i = 0; i < 4; i++)
#pragma unroll
            for (int j = 0; j < 4; j++)
                acc[i][j] = __builtin_amdgcn_mfma_f32_16x16x32_bf16(
                    af[i], bfr[j], acc[i][j], 0, 0, 0);
        __syncthreads();
    }

    const int crow = (lane >> 4) * 4;
    const int ccol = lane & 15;
#pragma unroll
    for (int i = 0; i < 4; i++)
#pragma unroll
        for (int j = 0; j < 4; j++) {
            const int n = n0 + n_off + j * 16 + ccol;
#pragma unroll
            for (int r = 0; r < 4; r++) {
                const int m = m0 + m_off + i * 16 + crow + r;
                if (BF16OUT)
                    ((unsigned short*)Cout)[(size_t)m * N + n] = f2bf(acc[i][j][r]);
                else
                    ((float*)Cout)[(size_t)m * N + n] = acc[i][j][r];
            }
        }
}

// ---------------------------------------------------------------------------
// Skinny dt projection, MFMA, fused sigmoid epilogue.
// ---------------------------------------------------------------------------
__global__ __launch_bounds__(256) void dtproj_mfma(const unsigned short* __restrict__ A,
                                                   const unsigned short* __restrict__ W,
                                                   const float* __restrict__ bias,
                                                   float* __restrict__ dtb,
                                                   int K) {
    __shared__ unsigned short As[128 * 32];
    __shared__ unsigned short Bs[32 * 32];
    const int tid = threadIdx.x;
    const int wave = tid >> 6, lane = tid & 63;
    const int quad = lane >> 4, l16 = lane & 15;
    const int m0 = blockIdx.x * 128;

    f32x4 acc[2][2];
#pragma unroll
    for (int i = 0; i < 2; i++)
#pragma unroll
        for (int j = 0; j < 2; j++) acc[i][j] = (f32x4){0.f, 0.f, 0.f, 0.f};

    for (int kt = 0; kt < K; kt += 32) {
#pragma unroll
        for (int u = 0; u < 2; u++) {
            const int f = u * 256 + tid;
            const int row = f >> 2, ke = (f & 3) * 8;
            gload16(A + (size_t)(m0 + row) * K + kt + ke, ((char*)As) + f * 16);
        }
        if (tid < 128) {
            const int row = tid >> 2, ke = (tid & 3) * 8;
            gload16(W + (size_t)row * K + kt + ke, ((char*)Bs) + tid * 16);
        }
        __syncthreads();
        short8 af[2], bfr[2];
#pragma unroll
        for (int i = 0; i < 2; i++)
            af[i] = *(const short8*)((const char*)As + (wave * 32 + i * 16 + l16) * 64 + quad * 16);
#pragma unroll
        for (int j = 0; j < 2; j++)
            bfr[j] = *(const short8*)((const char*)Bs + (j * 16 + l16) * 64 + quad * 16);
#pragma unroll
        for (int i = 0; i < 2; i++)
#pragma unroll
            for (int j = 0; j < 2; j++)
                acc[i][j] = __builtin_amdgcn_mfma_f32_16x16x32_bf16(
                    af[i], bfr[j], acc[i][j], 0, 0, 0);
        __syncthreads();
    }
#pragma unroll
    for (int i = 0; i < 2; i++)
#pragma unroll
        for (int j = 0; j < 2; j++) {
            const int h = j * 16 + l16;
            const float bh = bias[h];
#pragma unroll
            for (int r = 0; r < 4; r++) {
                const int m = m0 + wave * 32 + i * 16 + quad * 4 + r;
                dtb[(size_t)m * NHEADS + h] =
                    0.001f + 0.099f * sigm_(acc[i][j][r] + bh);
            }
        }
}

// ---------------------------------------------------------------------------
// Depthwise causal conv (K=4) + bias + SiLU, bf16 in/out.
// One thread = 4 consecutive rows x one 8-channel group, rolling register
// window: 7 coalesced 16B input loads + 1 weight gather per 4 outputs.
// ---------------------------------------------------------------------------
__global__ __launch_bounds__(256) void conv_silu_w(const unsigned short* __restrict__ xbc,
                                                   const float* __restrict__ cw,
                                                   const float* __restrict__ cb,
                                                   unsigned short* __restrict__ xssm,
                                                   unsigned short* __restrict__ Bb,
                                                   unsigned short* __restrict__ Cb) {
    const int idx = blockIdx.x * 256 + threadIdx.x;   // < (ROWS/4)*CGRP
    const int g = idx % CGRP;
    const int rowblk = idx / CGRP;
    const long row0 = (long)rowblk * 4;
    const int lbase = (int)(row0 & (LEN - 1));        // position within sequence
    const int j0 = g * 8;

    float4 wv[8];
    float cbv[8];
#pragma unroll
    for (int e = 0; e < 8; e++) {
        wv[e] = *(const float4*)(cw + (size_t)(j0 + e) * 4);
        cbv[e] = cb[j0 + e];
    }

    short8 win[4];
    const short8 zero8 = (short8){0, 0, 0, 0, 0, 0, 0, 0};
#pragma unroll
    for (int t = 0; t < 3; t++) {
        const int lr = lbase - 3 + t;
        win[t] = (lr >= 0) ? *(const short8*)(xbc + (row0 - 3 + t) * CONVDIM + j0)
                           : zero8;
    }
#pragma unroll
    for (int i = 0; i < 4; i++) {
        win[3] = *(const short8*)(xbc + (row0 + i) * CONVDIM + j0);
        short8 o;
#pragma unroll
        for (int e = 0; e < 8; e++) {
            float acc = cbv[e];
            acc += bf2f((unsigned short)win[0][e]) * wv[e].x;
            acc += bf2f((unsigned short)win[1][e]) * wv[e].y;
            acc += bf2f((unsigned short)win[2][e]) * wv[e].z;
            acc += bf2f((unsigned short)win[3][e]) * wv[e].w;
            o[e] = (short)f2bf(silu_(acc));
        }
        const long row = row0 + i;
        if (j0 < DINNER)
            *(short8*)(xssm + row * DINNER + j0) = o;
        else if (j0 < DINNER + DSTATE)
            *(short8*)(Bb + row * DSTATE + (j0 - DINNER)) = o;
        else
            *(short8*)(Cb + row * DSTATE + (j0 - DINNER - DSTATE)) = o;
        win[0] = win[1]; win[1] = win[2]; win[2] = win[3];
    }
}

__global__ __launch_bounds__(64) void acum_kernel(const float* __restrict__ dtb,
                                                  const float* __restrict__ A_log,
                                                  float* __restrict__ Acum) {
    const int c = blockIdx.x, h = blockIdx.y, b = blockIdx.z;
    const int q = threadIdx.x;
    const float Av = -expf(A_log[h]);
    float v = dtb[((size_t)b * LEN + c * QC + q) * NHEADS + h] * Av;
#pragma unroll
    for (int off = 1; off < 64; off <<= 1) {
        const float n = __shfl_up(v, off, 64);
        if (q >= off) v += n;
    }
    Acum[(((size_t)b * NHEADS + h) * NCHUNK + c) * QC + q] = v;
}

// ---------------------------------------------------------------------------
// MFMA chunk kernel (see R4 notes).
// ---------------------------------------------------------------------------
__global__ __launch_bounds__(256) void chunk_mfma(const unsigned short* __restrict__ xssm,
                                                  const unsigned short* __restrict__ Bb,
                                                  const unsigned short* __restrict__ Cb,
                                                  const float* __restrict__ dtb,
                                                  const float* __restrict__ Acum,
                                                  const float* __restrict__ Dskip,
                                                  unsigned short* __restrict__ Y,
                                                  unsigned short* __restrict__ states) {
    const int c = blockIdx.x, h = blockIdx.y, b = blockIdx.z;
    const int tid = threadIdx.x;
    const int wave = tid >> 6, lane = tid & 63;
    const int quad = lane >> 4, l16 = lane & 15;

    __shared__ __attribute__((aligned(16))) unsigned short Bsh[8704];
    __shared__ __attribute__((aligned(16))) unsigned short Csh[9216];
    __shared__ __attribute__((aligned(16))) unsigned short xTs[4608];
    __shared__ float ac[QC], dts[QC], decs[QC];

    const size_t rowbase = (size_t)b * LEN + c * QC;
    if (tid < QC) {
        ac[tid]  = Acum[(((size_t)b * NHEADS + h) * NCHUNK + c) * QC + tid];
        dts[tid] = dtb[(rowbase + tid) * NHEADS + h];
    }
#pragma unroll
    for (int u = 0; u < 4; u++) {
        const int vi = u * 256 + tid;
        const int s = vi >> 4, n0 = (vi & 15) * 8;
        *(short8*)&Bsh[s * PB + n0] = *(const short8*)(Bb + (rowbase + s) * DSTATE + n0);
        *(short8*)&Csh[s * PB + n0] = *(const short8*)(Cb + (rowbase + s) * DSTATE + n0);
    }
#pragma unroll
    for (int u = 0; u < 2; u++) {
        const int vi = u * 256 + tid;
        const int q = vi >> 3, p0 = (vi & 7) * 8;
        const short8 v = *(const short8*)(xssm + (rowbase + q) * DINNER + h * HDIM + p0);
#pragma unroll
        for (int j = 0; j < 8; j++) xTs[(p0 + j) * PT + q] = (unsigned short)v[j];
    }
    __syncthreads();
    if (tid < QC) decs[tid] = expf(ac[QC - 1] - ac[tid]) * dts[tid];

    // Phase 1: S = C . B^T
    f32x4 S[4];
#pragma unroll
    for (int j = 0; j < 4; j++) S[j] = (f32x4){0.f, 0.f, 0.f, 0.f};
    const int qa = wave * 16 + l16;
#pragma unroll
    for (int ks = 0; ks < 4; ks++) {
        const short8 a = *(const short8*)&Csh[qa * PB + ks * 32 + quad * 8];
#pragma unroll
        for (int j = 0; j < 4; j++) {
            const short8 bb = *(const short8*)&Bsh[(j * 16 + l16) * PB + ks * 32 + quad * 8];
            S[j] = __builtin_amdgcn_mfma_f32_16x16x32_bf16(a, bb, S[j], 0, 0, 0);
        }
    }
    unsigned short slv[4][4];
#pragma unroll
    for (int j = 0; j < 4; j++)
#pragma unroll
        for (int r = 0; r < 4; r++) {
            const int q = wave * 16 + quad * 4 + r, s = j * 16 + l16;
            const float v = (s <= q) ? S[j][r] * expf(ac[q] - ac[s]) * dts[s] : 0.f;
            slv[j][r] = f2bf(v);
        }
    __syncthreads();

    // B'[n][q] = B[q][n]*decs[q]
#pragma unroll
    for (int u = 0; u < 4; u++) {
        const int vi = u * 256 + tid;
        const int s = vi >> 4, n0 = (vi & 15) * 8;
        const short8 v = *(const short8*)&Bsh[s * PB + n0];
        const float d = decs[s];
#pragma unroll
        for (int j = 0; j < 8; j++)
            Csh[(n0 + j) * PT + s] = f2bf(bf2f((unsigned short)v[j]) * d);
    }
    __syncthreads();

#pragma unroll
    for (int j = 0; j < 4; j++)
#pragma unroll
        for (int r = 0; r < 4; r++)
            Bsh[(wave * 16 + quad * 4 + r) * PT + j * 16 + l16] = slv[j][r];
    __syncthreads();

    // Phase 2: Yd = SL . x
    f32x4 yd[4];
#pragma unroll
    for (int j = 0; j < 4; j++) yd[j] = (f32x4){0.f, 0.f, 0.f, 0.f};
#pragma unroll
    for (int ks = 0; ks < 2; ks++) {
        const short8 a = *(const short8*)&Bsh[qa * PT + ks * 32 + quad * 8];
#pragma unroll
        for (int j = 0; j < 4; j++) {
            const short8 xb = *(const short8*)&xTs[(j * 16 + l16) * PT + ks * 32 + quad * 8];
            yd[j] = __builtin_amdgcn_mfma_f32_16x16x32_bf16(a, xb, yd[j], 0, 0, 0);
        }
    }
    const float Dh = Dskip[h];
#pragma unroll
    for (int j = 0; j < 4; j++)
#pragma unroll
        for (int r = 0; r < 4; r++) {
            const int q = wave * 16 + quad * 4 + r, p = j * 16 + l16;
            const float v = yd[j][r] + Dh * bf2f(xTs[p * PT + q]);
            Y[(rowbase + q) * DINNER + h * HDIM + p] = f2bf(v);
        }

    // Phase 3: states = xT . B'
    f32x4 st[8];
#pragma unroll
    for (int j = 0; j < 8; j++) st[j] = (f32x4){0.f, 0.f, 0.f, 0.f};
#pragma unroll
    for (int ks = 0; ks < 2; ks++) {
        const short8 a = *(const short8*)&xTs[qa * PT + ks * 32 + quad * 8];
#pragma unroll
        for (int j = 0; j < 8; j++) {
            const short8 bb = *(const short8*)&Csh[(j * 16 + l16) * PT + ks * 32 + quad * 8];
            st[j] = __builtin_amdgcn_mfma_f32_16x16x32_bf16(a, bb, st[j], 0, 0, 0);
        }
    }
    const size_t sbase = (((size_t)b * NHEADS + h) * NCHUNK + c) * SDIM;
#pragma unroll
    for (int j = 0; j < 8; j++)
#pragma unroll
        for (int r = 0; r < 4; r++) {
            const int p = wave * 16 + quad * 4 + r, n = j * 16 + l16;
            states[sbase + (size_t)p * DSTATE + n] = f2bf(st[j][r]);
        }
}

// Sequential inter-chunk scan (bf16 storage, f32 carry)
__global__ __launch_bounds__(256) void scan_kernel(unsigned short* __restrict__ states,
                                                   const float* __restrict__ Acum) {
    __shared__ float dec[NCHUNK];
    const int bh = blockIdx.y;
    const int pn = blockIdx.x * 256 + threadIdx.x;
    if (threadIdx.x < NCHUNK)
        dec[threadIdx.x] = expf(Acum[((size_t)bh * NCHUNK + threadIdx.x) * QC + (QC - 1)]);
    __syncthreads();
    float carry = 0.f;
    const size_t base = (size_t)bh * NCHUNK * SDIM + pn;
    for (int c = 0; c < NCHUNK; c++) {
        const size_t idx = base + (size_t)c * SDIM;
        const float s = bf2f(states[idx]);
        states[idx] = f2bf(carry);
        carry = dec[c] * carry + s;
    }
}

// MFMA yo kernel: Yo[q][p] = eq[q] * sum_n C[q][n]*prev[p][n];  Y += Yo (bf16)
__global__ __launch_bounds__(256) void yo_mfma(const unsigned short* __restrict__ Cb,
                                               const unsigned short* __restrict__ prevs,
                                               const float* __restrict__ Acum,
                                               unsigned short* __restrict__ Y) {
    const int c = blockIdx.x, h = blockIdx.y, b = blockIdx.z;
    const int tid = threadIdx.x;
    const int wave = tid >> 6, lane = tid & 63;
    const int quad = lane >> 4, l16 = lane & 15;
    __shared__ __attribute__((aligned(16))) unsigned short Csh[8704];
    __shared__ __attribute__((aligned(16))) unsigned short Psh[8704];
    __shared__ float eq[QC];
    const size_t rowbase = (size_t)b * LEN + c * QC;
    const size_t pbase = (((size_t)b * NHEADS + h) * NCHUNK + c) * SDIM;
    if (tid < QC)
        eq[tid] = expf(Acum[(((size_t)b * NHEADS + h) * NCHUNK + c) * QC + tid]);
#pragma unroll
    for (int u = 0; u < 4; u++) {
        const int vi = u * 256 + tid;
        const int r = vi >> 4, n0 = (vi & 15) * 8;
        *(short8*)&Csh[r * PB + n0] = *(const short8*)(Cb + (rowbase + r) * DSTATE + n0);
        *(short8*)&Psh[r * PB + n0] = *(const short8*)(prevs + pbase + (size_t)r * DSTATE + n0);
    }
    __syncthreads();

    f32x4 acc[4];
#pragma unroll
    for (int j = 0; j < 4; j++) acc[j] = (f32x4){0.f, 0.f, 0.f, 0.f};
    const int qa = wave * 16 + l16;
#pragma unroll
    for (int ks = 0; ks < 4; ks++) {
        const short8 a = *(const short8*)&Csh[qa * PB + ks * 32 + quad * 8];
#pragma unroll
        for (int j = 0; j < 4; j++) {
            const short8 bb = *(const short8*)&Psh[(j * 16 + l16) * PB + ks * 32 + quad * 8];
            acc[j] = __builtin_amdgcn_mfma_f32_16x16x32_bf16(a, bb, acc[j], 0, 0, 0);
        }
    }
#pragma unroll
    for (int j = 0; j < 4; j++)
#pragma unroll
        for (int r = 0; r < 4; r++) {
            const int q = wave * 16 + quad * 4 + r, p = j * 16 + l16;
            const size_t off = (rowbase + q) * DINNER + h * HDIM + p;
            Y[off] = f2bf(bf2f(Y[off]) + eq[q] * acc[j][r]);
        }
}

// y = Y * silu(z); RMS-norm; write bf16 for GEMM2  (all bf16 I/O)
__global__ __launch_bounds__(256) void gate_rms(const unsigned short* __restrict__ Y,
                                                const unsigned short* __restrict__ zbf,
                                                const float* __restrict__ nw,
                                                unsigned short* __restrict__ ybf) {
    const int r = blockIdx.x, tid = threadIdx.x;
    float4 yv[2];
    float ss = 0.f;
#pragma unroll
    for (int u = 0; u < 2; u++) {
        const int col = u * 1024 + tid * 4;
        const ushort4 y4 = *(const ushort4*)(Y + (size_t)r * DINNER + col);
        const ushort4 z4 = *(const ushort4*)(zbf + (size_t)r * DINNER + col);
        float4 y;
        y.x = bf2f(y4.x) * silu_(bf2f(z4.x)); y.y = bf2f(y4.y) * silu_(bf2f(z4.y));
        y.z = bf2f(y4.z) * silu_(bf2f(z4.z)); y.w = bf2f(y4.w) * silu_(bf2f(z4.w));
        yv[u] = y;
        ss += y.x * y.x + y.y * y.y + y.z * y.z + y.w * y.w;
    }
#pragma unroll
    for (int off = 32; off; off >>= 1) ss += __shfl_xor(ss, off, 64);
    __shared__ float red[4];
    if ((tid & 63) == 0) red[tid >> 6] = ss;
    __syncthreads();
    ss = red[0] + red[1] + red[2] + red[3];
    const float scale = rsqrtf(ss / (float)DINNER + 1e-5f);
#pragma unroll
    for (int u = 0; u < 2; u++) {
        const int col = u * 1024 + tid * 4;
        const float4 w4 = *(const float4*)(nw + col);
        ushort4 o;
        o.x = f2bf(yv[u].x * scale * w4.x); o.y = f2bf(yv[u].y * scale * w4.y);
        o.z = f2bf(yv[u].z * scale * w4.z); o.w = f2bf(yv[u].w * scale * w4.w);
        *(ushort4*)(ybf + (size_t)r * DINNER + col) = o;
    }
}

// LayerNorm over D + residual (in place: outb == out is safe)
__global__ __launch_bounds__(256) void ln_res(const float* __restrict__ outb,
                                              const float* __restrict__ x,
                                              const float* __restrict__ lw,
                                              const float* __restrict__ lb,
                                              float* __restrict__ out) {
    const int r = blockIdx.x, tid = threadIdx.x;
    const int col = tid * 4;
    const float4 v = *(const float4*)(outb + (size_t)r * DMODEL + col);
    float s = v.x + v.y + v.z + v.w;
    float s2 = v.x * v.x + v.y * v.y + v.z * v.z + v.w * v.w;
#pragma unroll
    for (int off = 32; off; off >>= 1) {
        s += __shfl_xor(s, off, 64);
        s2 += __shfl_xor(s2, off, 64);
    }
    __shared__ float rs[4], rs2[4];
    if ((tid & 63) == 0) { rs[tid >> 6] = s; rs2[tid >> 6] = s2; }
    __syncthreads();
    s = rs[0] + rs[1] + rs[2] + rs[3];
    s2 = rs2[0] + rs2[1] + rs2[2] + rs2[3];
    const float mu = s / (float)DMODEL;
    const float var = s2 / (float)DMODEL - mu * mu;
    const float inv = rsqrtf(var + 1e-5f);
    const float4 xw = *(const float4*)(x + (size_t)r * DMODEL + col);
    const float4 w4 = *(const float4*)(lw + col);
    const float4 b4 = *(const float4*)(lb + col);
    float4 o;
    o.x = xw.x + (v.x - mu) * inv * w4.x + b4.x;
    o.y = xw.y + (v.y - mu) * inv * w4.y + b4.y;
    o.z = xw.z + (v.z - mu) * inv * w4.z + b4.z;
    o.w = xw.w + (v.w - mu) * inv * w4.w + b4.w;
    *(float4*)(out + (size_t)r * DMODEL + col) = o;
}

extern "C" void kernel_launch(void* const* d_in, const int* in_sizes, int n_in,
                              void* d_out, int out_size, void* d_ws, size_t ws_size,
                              hipStream_t stream) {
    const float* x          = (const float*)d_in[0];
    const float* in_proj_w  = (const float*)d_in[1];
    const float* conv_w     = (const float*)d_in[2];
    const float* conv_b     = (const float*)d_in[3];
    const float* dt_bias    = (const float*)d_in[4];
    const float* A_log      = (const float*)d_in[5];
    const float* D_skip     = (const float*)d_in[6];
    const float* norm_w     = (const float*)d_in[7];
    const float* out_proj_w = (const float*)d_in[8];
    const float* ln_w       = (const float*)d_in[9];
    const float* ln_b       = (const float*)d_in[10];
    float* out = (float*)d_out;
    float* ws = (float*)d_ws;

    // Workspace layout (float units). ~209 MB.
    size_t off = 0;
    unsigned short* zbf     = (unsigned short*)(ws + off); off += (size_t)ROWS * DINNER / 2;
    unsigned short* xssm_bf = (unsigned short*)(ws + off); off += (size_t)ROWS * DINNER / 2;
    unsigned short* uni     = (unsigned short*)(ws + off); off += (size_t)ROWS * CONVDIM / 2;
    unsigned short* Bb_bf   = (unsigned short*)(ws + off); off += (size_t)ROWS * DSTATE / 2;
    unsigned short* Cb_bf   = (unsigned short*)(ws + off); off += (size_t)ROWS * DSTATE / 2;
    float* dtb   = ws + off; off += (size_t)ROWS * NHEADS;
    float* Acum  = ws + off; off += (size_t)BSZ * NHEADS * NCHUNK * QC;
    unsigned short* x_bf  = (unsigned short*)(ws + off); off += (size_t)ROWS * DMODEL / 2;
    unsigned short* wi_bf = (unsigned short*)(ws + off); off += (size_t)4384 * DMODEL / 2;
    unsigned short* wo_bf = (unsigned short*)(ws + off); off += (size_t)DMODEL * DINNER / 2;
    unsigned short* states = (unsigned short*)(ws + off); off += (size_t)BSZ * NHEADS * NCHUNK * SDIM / 2;
    const size_t need_bytes = off * sizeof(float);
    if (ws_size < need_bytes) return;   // fail cleanly instead of faulting

    unsigned short* xbc_bf = uni;        // dies after conv
    unsigned short* Ybf    = uni;        // chunk output overlays dead xbc
    unsigned short* ybf    = xssm_bf;    // gate output overlays dead xssm

    // Casts
    cast_bf16<<<(ROWS * DMODEL / 4 + 255) / 256, 256, 0, stream>>>(x, x_bf, ROWS * DMODEL / 4);
    cast_bf16<<<(4384 * DMODEL / 4 + 255) / 256, 256, 0, stream>>>(in_proj_w, wi_bf, 4384 * DMODEL / 4);
    cast_bf16<<<(DMODEL * DINNER / 4 + 255) / 256, 256, 0, stream>>>(out_proj_w, wo_bf, DMODEL * DINNER / 4);

    // In-projection (bf16 MFMA): z (bf16), xBC (bf16), dt (MFMA + fused sigmoid)
    gemm_bt_mfma<true><<<dim3(DINNER / 128, ROWS / 128), 256, 0, stream>>>(
        x_bf, wi_bf, zbf, DINNER, DMODEL);
    gemm_bt_mfma<true><<<dim3(CONVDIM / 128, ROWS / 128), 256, 0, stream>>>(
        x_bf, wi_bf + (size_t)DINNER * DMODEL, xbc_bf, CONVDIM, DMODEL);
    dtproj_mfma<<<ROWS / 128, 256, 0, stream>>>(
        x_bf, wi_bf + (size_t)(DINNER + CONVDIM) * DMODEL, dt_bias, dtb, DMODEL);

    conv_silu_w<<<(ROWS / 4) * CGRP / 256, 256, 0, stream>>>(
        xbc_bf, conv_w, conv_b, xssm_bf, Bb_bf, Cb_bf);
    acum_kernel<<<dim3(NCHUNK, NHEADS, BSZ), 64, 0, stream>>>(dtb, A_log, Acum);
    chunk_mfma<<<dim3(NCHUNK, NHEADS, BSZ), 256, 0, stream>>>(
        xssm_bf, Bb_bf, Cb_bf, dtb, Acum, D_skip, Ybf, states);
    scan_kernel<<<dim3(SDIM / 256, BSZ * NHEADS), 256, 0, stream>>>(states, Acum);
    yo_mfma<<<dim3(NCHUNK, NHEADS, BSZ), 256, 0, stream>>>(Cb_bf, states, Acum, Ybf);
    gate_rms<<<ROWS, 256, 0, stream>>>(Ybf, zbf, norm_w, ybf);

    // Out-projection (bf16 MFMA) into d_out, then LN in place
    gemm_bt_mfma<false><<<dim3(DMODEL / 128, ROWS / 128), 256, 0, stream>>>(
        ybf, wo_bf, out, DMODEL, DINNER);
    ln_res<<<ROWS, 256, 0, stream>>>(out, x, ln_w, ln_b, out);
}